// Round 7
// baseline (99.310 us; speedup 1.0000x reference)
//
#include <hip/hip_runtime.h>

// IDWT3D (haar, tiny): out[T,H,W,c] = x[T/2,H/2,W/2,c] * (1/sqrt2)^3
// x: (16,128,128,64) f32 -> out: (32,256,256,64) f32
//
// R7: VALU-minimized addressing. R4's loop was VALU-bound on per-store
// 64-bit address math (~26 VALU/iter = 52 SIMD-cyc vs 9 VMEM-cyc; ~89 us
// predicted ~= 92.7 us measured). Here every address is a 32-bit byte
// offset from the uniform kernel-arg base (saddr-form global stores), the
// per-iteration stride only advances t (t += 2: idx < 2^19 so t0 in {0,1},
// t = t0+2k <= 15, no carries into h/w/c4), so offsets update with single
// 32-bit adds and the decode runs ONCE per thread.
// Loads temporal (64 MiB input stays L3-resident across graph replays);
// stores nontemporal (512 MiB write-once; don't evict input from L3).
//
// Input  f4 (t,h,w,c4) = (t<<18)+(h<<11)+(w<<4)+c4 ; byte = idx<<4
// Output f4 (T,H,W,c4) = (T<<20)+(H<<12)+(W<<4)+c4 ; byte = idx<<4
// Per iter: in_byte += 8 MiB (1<<23), out_byte += 64 MiB (1<<26).
// Duplicate offsets: W+1 = +256 B, H+1 = +65536 B, T+1 = +16 MiB.

typedef float f4 __attribute__((ext_vector_type(4)));

__global__ void __launch_bounds__(256) idwt3_haar_saddr(
        const char* __restrict__ cin, char* __restrict__ cout) {
    const float s = 0.35355339059327379f;  // (1/sqrt2)^3
    unsigned idx = blockIdx.x * 256 + threadIdx.x;      // < 2^19
    unsigned c4 = idx & 15;
    unsigned w  = (idx >> 4) & 127;
    unsigned h  = (idx >> 11) & 127;
    unsigned t0 = idx >> 18;                            // 0 or 1
    unsigned in_off  = idx << 4;                                    // bytes
    unsigned out_off = ((t0 << 21) + (h << 13) + (w << 5) + c4) << 4; // bytes

#pragma unroll
    for (int k = 0; k < 8; ++k) {
        f4 x = *(const f4*)(cin + in_off);              // temporal, L3-hit
        x *= s;
        unsigned b = out_off;
        __builtin_nontemporal_store(x, (f4*)(cout + b));                          // (2t,2h,2w)
        __builtin_nontemporal_store(x, (f4*)(cout + b + 256u));                   // W+1
        __builtin_nontemporal_store(x, (f4*)(cout + b + 65536u));                 // H+1
        __builtin_nontemporal_store(x, (f4*)(cout + b + 65536u + 256u));
        __builtin_nontemporal_store(x, (f4*)(cout + b + 16777216u));              // T+1
        __builtin_nontemporal_store(x, (f4*)(cout + b + 16777216u + 256u));
        __builtin_nontemporal_store(x, (f4*)(cout + b + 16777216u + 65536u));
        __builtin_nontemporal_store(x, (f4*)(cout + b + 16777216u + 65536u + 256u));
        in_off  += (1u << 23);   // next t-pair: +8 MiB
        out_off += (1u << 26);   // +64 MiB
    }
}

extern "C" void kernel_launch(void* const* d_in, const int* in_sizes, int n_in,
                              void* d_out, int out_size, void* d_ws, size_t ws_size,
                              hipStream_t stream) {
    const char* in = (const char*)d_in[0];
    char* out = (char*)d_out;
    // 2048 blocks x 256 = 2^19 threads, exactly 8 iters each (2^22 input f4)
    idwt3_haar_saddr<<<2048, 256, 0, stream>>>(in, out);
}